// Round 3
// baseline (1388.929 us; speedup 1.0000x reference)
//
#include <hip/hip_runtime.h>
#include <hip/hip_bf16.h>

// Problem constants (fixed by reference): B=4, S=6000, H=12, D=128, HID=1536
// Reference dtype is float32 throughout -> d_in / d_out are fp32.
#define BATCH 4
#define SEQ   6000
#define NHEAD 12
#define HDIM  128
#define HID   1536
#define CHUNK 12
#define CTXW  24
#define NBLK  500            // SEQ / CHUNK
#define MROWS (BATCH * SEQ)  // 24000

#define Q_SCALE_D (0.08838834764831845 / 0.6931471805599453)   // D^-0.5 / ln2
#define K_SCALE_D (1.3132616875182228 / 0.6931471805599453)    // ln(1+e) / ln2

typedef __bf16 bf16x8 __attribute__((ext_vector_type(8)));
typedef float  floatx4 __attribute__((ext_vector_type(4)));

// Sanitizer: clamps to +-1e15 and maps NaN to -1e15 (fmaxf = IEEE maxNum:
// max(NaN,x)=x). No-op on sane data; guarantees finite output even if the
// dtype interpretation is wrong (diagnostic property).
#define SAN_LIM 1e15f
__device__ __forceinline__ float san(float f) {
    return fminf(fmaxf(f, -SAN_LIM), SAN_LIM);
}

// ---------------------------------------------------------------------------
// qscale[d] = Q_SCALE * softplus(per_dim_scale[d])
// ---------------------------------------------------------------------------
__global__ void qscale_kernel(const float* __restrict__ pds,
                              float* __restrict__ qs) {
    int d = threadIdx.x;
    float x = san(pds[d]);
    float sp = (x > 20.0f) ? x : log1pf(expf(x));
    qs[d] = san((float)Q_SCALE_D * sp);
}

// ---------------------------------------------------------------------------
// C[M,N] = A[M,K] @ W[N,K]^T. W is fp32 (converted to bf16 during staging).
// ADT: 1 = A fp32 (convert in staging), 0 = A bf16.
// CDT: 0 = C bf16, 1 = C fp32.
// 128x128 tile, BK=32, 256 thr = 4 waves, 4x4 16x16x32 bf16 MFMA, fp32 accum.
// Epilogue: * cscale, and * colscale[col & 127] if colscale != nullptr.
// ---------------------------------------------------------------------------
template<int ADT, int CDT>
__device__ __forceinline__ void gemm_core(
    const void* __restrict__ Av,
    const float* __restrict__ W,
    void* __restrict__ Cv,
    int M, int N, int K,
    const float* __restrict__ colscale, float cscale)
{
    __shared__ __align__(16) __hip_bfloat16 As[128 * 32];
    __shared__ __align__(16) __hip_bfloat16 Bs[128 * 32];

    const int tid   = threadIdx.x;
    const int tileM = blockIdx.y * 128;
    const int tileN = blockIdx.x * 128;

    const int wave = tid >> 6;
    const int lane = tid & 63;
    const int wr   = (wave >> 1) << 6;   // wave row offset (0/64)
    const int wc   = (wave & 1) << 6;    // wave col offset (0/64)
    const int frow = lane & 15;          // fragment row/col within 16
    const int fk   = (lane >> 4) << 3;   // fragment k offset (0,8,16,24)

    floatx4 acc[4][4] = {};

    for (int k0 = 0; k0 < K; k0 += 32) {
        __syncthreads();
        // ---- stage A tile (128 x 32) ----
        if (ADT == 1) {
            const float* A = (const float*)Av;
            #pragma unroll
            for (int g = 0; g < 4; ++g) {
                int gi = tid + 256 * g;          // 0..1023 granules of 4 floats
                int r  = gi >> 3;
                int c4 = (gi & 7) << 2;
                int rr = tileM + r; if (rr > M - 1) rr = M - 1;
                float4 f = *(const float4*)(A + (size_t)rr * K + k0 + c4);
                union { __hip_bfloat16 h[4]; uint2 u; } cv;
                cv.h[0] = __float2bfloat16(san(f.x));
                cv.h[1] = __float2bfloat16(san(f.y));
                cv.h[2] = __float2bfloat16(san(f.z));
                cv.h[3] = __float2bfloat16(san(f.w));
                *(uint2*)&As[r * 32 + c4] = cv.u;
            }
        } else {
            const __hip_bfloat16* A = (const __hip_bfloat16*)Av;
            #pragma unroll
            for (int g = 0; g < 2; ++g) {
                int gi = tid + 256 * g;          // 0..511 granules of 8 bf16
                int r  = gi >> 2;
                int c8 = (gi & 3) << 3;
                int rr = tileM + r; if (rr > M - 1) rr = M - 1;
                *(bf16x8*)&As[r * 32 + c8] =
                    *(const bf16x8*)(A + (size_t)rr * K + k0 + c8);
            }
        }
        // ---- stage B tile (weights, always fp32; N is a multiple of 128) ----
        #pragma unroll
        for (int g = 0; g < 4; ++g) {
            int gi = tid + 256 * g;
            int r  = gi >> 3;
            int c4 = (gi & 7) << 2;
            int rr = tileN + r;
            float4 f = *(const float4*)(W + (size_t)rr * K + k0 + c4);
            union { __hip_bfloat16 h[4]; uint2 u; } cv;
            cv.h[0] = __float2bfloat16(san(f.x));
            cv.h[1] = __float2bfloat16(san(f.y));
            cv.h[2] = __float2bfloat16(san(f.z));
            cv.h[3] = __float2bfloat16(san(f.w));
            *(uint2*)&Bs[r * 32 + c4] = cv.u;
        }
        __syncthreads();

        bf16x8 af[4], bfr[4];
        #pragma unroll
        for (int i = 0; i < 4; ++i)
            af[i] = *(const bf16x8*)&As[(wr + i * 16 + frow) * 32 + fk];
        #pragma unroll
        for (int j = 0; j < 4; ++j)
            bfr[j] = *(const bf16x8*)&Bs[(wc + j * 16 + frow) * 32 + fk];
        #pragma unroll
        for (int i = 0; i < 4; ++i)
            #pragma unroll
            for (int j = 0; j < 4; ++j)
                acc[i][j] = __builtin_amdgcn_mfma_f32_16x16x32_bf16(
                    af[i], bfr[j], acc[i][j], 0, 0, 0);
    }

    // epilogue: C/D layout col=lane&15, row=(lane>>4)*4+r
    #pragma unroll
    for (int i = 0; i < 4; ++i) {
        #pragma unroll
        for (int r = 0; r < 4; ++r) {
            int row = tileM + wr + i * 16 + ((lane >> 4) << 2) + r;
            if (row < M) {
                #pragma unroll
                for (int j = 0; j < 4; ++j) {
                    int col = tileN + wc + j * 16 + (lane & 15);
                    float v = acc[i][j][r] * cscale;
                    if (colscale) v *= colscale[col & 127];
                    if (CDT == 0)
                        ((__hip_bfloat16*)Cv)[(size_t)row * N + col] =
                            __float2bfloat16(v);
                    else
                        ((float*)Cv)[(size_t)row * N + col] = v;
                }
            }
        }
    }
}

__global__ __launch_bounds__(256, 2)
void gemm_f_b(const float* __restrict__ A, const float* __restrict__ W,
              __hip_bfloat16* __restrict__ C,
              int M, int N, int K,
              const float* __restrict__ colscale, float cscale) {
    gemm_core<1, 0>(A, W, C, M, N, K, colscale, cscale);
}

__global__ __launch_bounds__(256, 2)
void gemm_b_f(const __hip_bfloat16* __restrict__ A, const float* __restrict__ W,
              float* __restrict__ C, int M, int N, int K) {
    gemm_core<0, 1>(A, W, C, M, N, K, nullptr, 1.0f);
}

__global__ __launch_bounds__(256, 2)
void gemm_qkv(const float* __restrict__ x,
              const float* __restrict__ Wq,
              const float* __restrict__ Wk,
              const float* __restrict__ Wv,
              __hip_bfloat16* __restrict__ Q,
              __hip_bfloat16* __restrict__ Kb,
              __hip_bfloat16* __restrict__ Vb,
              const float* __restrict__ qscale,
              int M, int N, int K) {
    const float* W;
    __hip_bfloat16* C;
    const float* cs = nullptr;
    float sc = 1.0f;
    if (blockIdx.z == 0)      { W = Wq; C = Q;  cs = qscale; }
    else if (blockIdx.z == 1) { W = Wk; C = Kb; sc = (float)K_SCALE_D; }
    else                      { W = Wv; C = Vb; }
    gemm_core<1, 0>(x, W, C, M, N, K, cs, sc);
}

// ---------------------------------------------------------------------------
// Attention: one block per (b_local, chunk n, head h). All buffers bf16.
// Query q attends to dist j in [0,12): key row g = n*12 + q - j, valid iff
// g >= 0. logit = q . (k[g] + rel_k[12-j]); tanh softcap 50; softmax;
// out = p @ v. O may alias Q (Q fully staged to LDS behind barrier first).
// ---------------------------------------------------------------------------
__global__ __launch_bounds__(256)
void attn_kernel(const __hip_bfloat16* __restrict__ Q,
                 const __hip_bfloat16* __restrict__ Kt,
                 const __hip_bfloat16* __restrict__ Vt,
                 const __hip_bfloat16* __restrict__ R,   // [24][1536] rel_k
                 __hip_bfloat16* __restrict__ O)
{
    const int tid = threadIdx.x;
    int idx = blockIdx.x;
    const int h = idx % NHEAD;  idx /= NHEAD;
    const int n = idx % NBLK;   idx /= NBLK;
    const int b = idx;                       // phase-local batch index

    __shared__ __align__(16) __hip_bfloat16 qs[CHUNK * HDIM];
    __shared__ __align__(16) __hip_bfloat16 ks[23 * HDIM];
    __shared__ __align__(16) __hip_bfloat16 vs[23 * HDIM];
    __shared__ __align__(16) __hip_bfloat16 rs[CHUNK * HDIM]; // rs[j]=rel_k[12-j]
    __shared__ float lg[CHUNK][CHUNK];

    const size_t rowbase = (size_t)b * SEQ + (size_t)n * CHUNK;
    const int hoff = h * HDIM;

    #pragma unroll
    for (int it = 0; it < 3; ++it) {
        int i = it * 256 + tid;
        int row = i >> 6;
        int cu  = i & 63;
        ((unsigned int*)qs)[i] =
            *(const unsigned int*)(Q + (rowbase + row) * HID + hoff + cu * 2);
    }
    #pragma unroll
    for (int it = 0; it < 6; ++it) {
        int i = it * 256 + tid;
        if (i < 1472) {
            int row = i >> 6;
            int cu  = i & 63;
            int g = n * CHUNK + row - 11;
            unsigned int kval = 0u, vval = 0u;
            if (g >= 0) {
                size_t off = ((size_t)b * SEQ + g) * HID + hoff + cu * 2;
                kval = *(const unsigned int*)(Kt + off);
                vval = *(const unsigned int*)(Vt + off);
            }
            ((unsigned int*)ks)[i] = kval;
            ((unsigned int*)vs)[i] = vval;
        }
    }
    #pragma unroll
    for (int it = 0; it < 3; ++it) {
        int i = it * 256 + tid;
        int j  = i >> 6;
        int cu = i & 63;
        ((unsigned int*)rs)[i] =
            *(const unsigned int*)(R + (size_t)(12 - j) * HID + hoff + cu * 2);
    }
    __syncthreads();

    if (tid < CHUNK * CHUNK) {
        int q = tid / CHUNK, j = tid % CHUNK;
        bool valid = (n > 0) || (j <= q);
        float acc = 0.0f;
        if (valid) {
            int krow = q + 11 - j;
            const __hip_bfloat16* qp = qs + q * HDIM;
            const __hip_bfloat16* kp = ks + krow * HDIM;
            const __hip_bfloat16* rp = rs + j * HDIM;
            #pragma unroll 16
            for (int d = 0; d < HDIM; ++d)
                acc += __bfloat162float(qp[d]) *
                       (__bfloat162float(kp[d]) + __bfloat162float(rp[d]));
            acc = tanhf(acc * 0.02f) * 50.0f;
        }
        lg[q][j] = valid ? acc : -1e30f;
    }
    __syncthreads();

    if (tid < CHUNK) {
        float m = -1e30f;
        #pragma unroll
        for (int j = 0; j < CHUNK; ++j) m = fmaxf(m, lg[tid][j]);
        float e[CHUNK];
        float s = 0.0f;
        #pragma unroll
        for (int j = 0; j < CHUNK; ++j) { e[j] = expf(lg[tid][j] - m); s += e[j]; }
        float inv = 1.0f / s;
        #pragma unroll
        for (int j = 0; j < CHUNK; ++j) lg[tid][j] = e[j] * inv;
    }
    __syncthreads();

    #pragma unroll
    for (int it = 0; it < 6; ++it) {
        int i = it * 256 + tid;
        int q = i >> 7, d = i & 127;
        float acc = 0.0f;
        #pragma unroll
        for (int j = 0; j < CHUNK; ++j)
            acc += lg[q][j] * __bfloat162float(vs[(q + 11 - j) * HDIM + d]);
        O[(rowbase + q) * HID + hoff + d] = __float2bfloat16(san(acc));
    }
}

// ---------------------------------------------------------------------------
extern "C" void kernel_launch(void* const* d_in, const int* in_sizes, int n_in,
                              void* d_out, int out_size, void* d_ws, size_t ws_size,
                              hipStream_t stream) {
    const float* x     = (const float*)d_in[0];
    const float* pos   = (const float*)d_in[1];
    const float* Wq    = (const float*)d_in[2];
    const float* Wk    = (const float*)d_in[3];
    const float* Wv    = (const float*)d_in[4];
    const float* Wrel  = (const float*)d_in[5];
    const float* Wpost = (const float*)d_in[6];
    const float* pds   = (const float*)d_in[7];
    float* out = (float*)d_out;

    // ws: [qscale 1024B][Rk bf16 73728B][Qb bf16][Kb bf16]
    // V (bf16) lives in the TAIL of the fp32 d_out buffer; it is dead before
    // any phase's post-GEMM writes overlap it (only the last phase's output
    // region covers the tail, and V is consumed by attention first).
    // Attention output O aliases Qb.
    char* ws = (char*)d_ws;
    float* qscale      = (float*)ws;
    __hip_bfloat16* Rk = (__hip_bfloat16*)(ws + 1024);
    __hip_bfloat16* Qb = (__hip_bfloat16*)(ws + 1024 + 73728);

    const size_t base = 1024 + 73728;
    const size_t phase1_bytes = (size_t)SEQ * HID * 2;   // per-batch bf16 bytes
    int phases;
    if      (ws_size >= base + 2 * 4 * phase1_bytes) phases = 1;  // ~147.5 MB
    else if (ws_size >= base + 2 * 2 * phase1_bytes) phases = 2;  // ~73.8 MB
    else                                             phases = 4;  // ~36.9 MB
    const int    Bp = BATCH / phases;
    const size_t Mp = (size_t)Bp * SEQ;
    const size_t phase_bytes = Mp * HID * 2;

    __hip_bfloat16* Kb = Qb + Mp * HID;
    __hip_bfloat16* Vb =
        (__hip_bfloat16*)((char*)d_out + (size_t)out_size * 4 - phase_bytes);

    qscale_kernel<<<1, 128, 0, stream>>>(pds, qscale);
    gemm_f_b<<<dim3(HID / 128, 1, 1), 256, 0, stream>>>(
        pos, Wrel, Rk, CTXW, HID, HID, nullptr, 1.0f);

    for (int p = 0; p < phases; ++p) {
        const float* xp = x + (size_t)p * Mp * HID;
        dim3 gqkv(HID / 128, (unsigned)((Mp + 127) / 128), 3);
        gemm_qkv<<<gqkv, 256, 0, stream>>>(xp, Wq, Wk, Wv, Qb, Kb, Vb, qscale,
                                           (int)Mp, HID, HID);

        attn_kernel<<<Bp * NBLK * NHEAD, 256, 0, stream>>>(Qb, Kb, Vb, Rk, Qb);

        gemm_b_f<<<dim3(HID / 128, (unsigned)((Mp + 127) / 128), 1), 256, 0,
                   stream>>>(Qb, Wpost, out + (size_t)p * Mp * HID,
                             (int)Mp, HID, HID);
    }
}